// Round 7
// baseline (1355.418 us; speedup 1.0000x reference)
//
#include <hip/hip_runtime.h>
#include <math.h>

namespace {

constexpr int B = 4, N = 1024, D = 512, H = 8, DHd = 64, L = 6, DFFd = 2048;
constexpr int M = B * N;           // 4096
constexpr int QKVS = 3 * D;        // 1536, qkv row stride
constexpr float NEG = -1000000000.0f;
constexpr float R2c = 100.0f;

typedef __attribute__((ext_vector_type(8))) short bf16x8;
typedef __attribute__((ext_vector_type(4))) float f32x4;
typedef __attribute__((ext_vector_type(16))) float f32x16;

__device__ __forceinline__ short f2bf(float f) {
  union { float f; unsigned u; } c; c.f = f;
  unsigned r = (c.u + 0x7fffu + ((c.u >> 16) & 1u)) >> 16;
  return (short)r;
}

__device__ __forceinline__ float bf2f(short s) {
  union { unsigned u; float f; } c;
  c.u = ((unsigned)(unsigned short)s) << 16;
  return c.f;
}

__device__ __forceinline__ float gelu_f(float x) {
  return 0.5f * x * (1.0f + erff(x * 0.70710678118654752f));
}

// ---------------- bias: (B,N,N) additive mask, bf16 ----------------
__global__ __launch_bounds__(256) void bias_kernel(
    const float* __restrict__ xy, const int* __restrict__ alive,
    const int* __restrict__ species, short* __restrict__ bias)
{
  int j = blockIdx.x * 256 + threadIdx.x;
  int i = blockIdx.y;
  int b = blockIdx.z;
  float xi = xy[((size_t)b * N + i) * 2 + 0];
  float yi = xy[((size_t)b * N + i) * 2 + 1];
  float xj = xy[((size_t)b * N + j) * 2 + 0];
  float yj = xy[((size_t)b * N + j) * 2 + 1];
  float dx = xi - xj, dy = yi - yj;
  float d2 = dx * dx + dy * dy;
  float bv = 0.0f;
  if (alive[b * N + j] == 0) bv += NEG;
  if (d2 > R2c) bv += NEG;
  int si = species[b * N + i], sj = species[b * N + j];
  bool ia = si < 2, ip = si == 2, ja = sj < 2, jp = sj == 2;
  if ((ia && jp) || (ip && ja)) bv += NEG;
  bias[((size_t)b * N + i) * N + j] = f2bf(bv);
}

// ---------------- weight prep: fp32 (K x Nc) -> bf16 transposed (Nc x K) ----------------
__global__ __launch_bounds__(256) void wprep_kernel(
    const float* __restrict__ src, short* __restrict__ dst,
    int K, int Nc, size_t srcLS, size_t dstLS)
{
  __shared__ float t[32][33];
  int k0 = blockIdx.x * 32, n0 = blockIdx.y * 32;
  src += (size_t)blockIdx.z * srcLS;
  dst += (size_t)blockIdx.z * dstLS;
  int r = threadIdx.x >> 5, c = threadIdx.x & 31;  // r: 0..7
#pragma unroll
  for (int i = 0; i < 4; ++i)
    t[r + i * 8][c] = src[(size_t)(k0 + r + i * 8) * Nc + n0 + c];
  __syncthreads();
#pragma unroll
  for (int i = 0; i < 4; ++i)
    dst[(size_t)(n0 + r + i * 8) * K + k0 + c] = f2bf(t[c][r + i * 8]);
}

// ---------------- LayerNorm: one wave per row of 512; bf16 or fp32 out ----------------
__global__ __launch_bounds__(64) void ln_kernel(
    const float* __restrict__ x, const float* __restrict__ g,
    const float* __restrict__ be, float* __restrict__ outf,
    short* __restrict__ outb)
{
  int row = blockIdx.x;
  int tid = threadIdx.x;
  const float* xr = x + (size_t)row * D;
  float v[8];
  float sum = 0.f;
#pragma unroll
  for (int i = 0; i < 8; ++i) { v[i] = xr[tid + i * 64]; sum += v[i]; }
#pragma unroll
  for (int off = 32; off > 0; off >>= 1) sum += __shfl_down(sum, off);
  sum = __shfl(sum, 0);
  float mean = sum * (1.0f / D);
  float vs = 0.f;
#pragma unroll
  for (int i = 0; i < 8; ++i) { float d = v[i] - mean; vs += d * d; }
#pragma unroll
  for (int off = 32; off > 0; off >>= 1) vs += __shfl_down(vs, off);
  vs = __shfl(vs, 0);
  float rstd = rsqrtf(vs * (1.0f / D) + 1e-5f);
#pragma unroll
  for (int i = 0; i < 8; ++i) {
    int c = tid + i * 64;
    float o = (v[i] - mean) * rstd * g[c] + be[c];
    if (outb) outb[(size_t)row * D + c] = f2bf(o);
    else      outf[(size_t)row * D + c] = o;
  }
}

// ---------------- split-K bf16 MFMA GEMM: barrier-free K-loop, dist-3 pipeline ----------------
// Block = 64x64 C-tile, 4 waves; wave w accumulates K-slice [w*K/4,(w+1)*K/4)
// into a full 64x64 partial (2x2 mfma_f32_32x32x16_bf16). BK=16 chunks staged
// into 4 wave-private LDS buffers via global_load_lds; issue chunk c+3, wait
// vmcnt(12) -> 3 chunks of slack (covers L2/L3 latency). No intra-loop barriers.
// One __syncthreads, then padded-LDS 4-way reduction + fused epilogue.
// mode 0: Cb=bf16(acc); mode 1: Cf=acc+bvec+Cf (in-place); mode 2: Cb=bf16(gelu(acc+bvec)).
__global__ __launch_bounds__(256, 2) void gemm_sk_kernel(
    const short* __restrict__ A, const short* __restrict__ Bt,
    const float* __restrict__ bvec, float* __restrict__ Cf,
    short* __restrict__ Cb, int K, int Nc, int mode)
{
  // per-wave slot 17408 B: staging = 4 bufs x (2KB A + 2KB B) = 16 KB;
  // reduction float[64][68] (17408 B) reuses the slot after the main loop.
  __shared__ __align__(16) char smem[4 * 17408];
  const int bm = blockIdx.y * 64, bn = blockIdx.x * 64;
  const int t = threadIdx.x, wave = t >> 6, lane = t & 63;
  const int half = lane >> 5;          // k-half for 32x32x16 frags
  const int l32 = lane & 31;           // m or n within tile
  const int srow2 = lane >> 1, sseg2 = lane & 1;  // staging coords (rows of 32B)

  char* slot = smem + wave * 17408;
  const int kw0 = wave * (K >> 2);
  const int nch = K >> 6;              // chunks of 16 per wave (>=8)

  const short* Ab = A + (size_t)(bm + srow2) * K + kw0 + sseg2 * 8;
  const short* Bb = Bt + (size_t)(bn + srow2) * K + kw0 + sseg2 * 8;

  auto issue = [&](int q, int c) {
    char* ab = slot + q * 4096;
    const int kc = c << 4;
#pragma unroll
    for (int i = 0; i < 2; ++i) {
      __builtin_amdgcn_global_load_lds(
          (const __attribute__((address_space(1))) void*)(Ab + (size_t)i * 32 * K + kc),
          (__attribute__((address_space(3))) void*)(ab + i * 1024), 16, 0, 0);
    }
#pragma unroll
    for (int i = 0; i < 2; ++i) {
      __builtin_amdgcn_global_load_lds(
          (const __attribute__((address_space(1))) void*)(Bb + (size_t)i * 32 * K + kc),
          (__attribute__((address_space(3))) void*)(ab + 2048 + i * 1024), 16, 0, 0);
    }
  };

  f32x16 acc[2][2];
#pragma unroll
  for (int i = 0; i < 2; ++i)
#pragma unroll
    for (int j = 0; j < 2; ++j)
#pragma unroll
      for (int r = 0; r < 16; ++r) acc[i][j][r] = 0.f;

  issue(0, 0);
  issue(1, 1);
  issue(2, 2);
  for (int c = 0; c < nch; ++c) {
    const int q = c & 3;
    const int cn = (c + 3 < nch) ? c + 3 : nch - 1;  // tail: re-read into consumed buf
    issue((c + 3) & 3, cn);
    asm volatile("s_waitcnt vmcnt(12)" ::: "memory");  // chunk c's 4 loads landed
    const short* As = (const short*)(slot + q * 4096);
    const short* Bs = (const short*)(slot + q * 4096 + 2048);
    bf16x8 a0 = *(const bf16x8*)&As[(l32) * 16 + half * 8];
    bf16x8 a1 = *(const bf16x8*)&As[(32 + l32) * 16 + half * 8];
    bf16x8 b0 = *(const bf16x8*)&Bs[(l32) * 16 + half * 8];
    bf16x8 b1 = *(const bf16x8*)&Bs[(32 + l32) * 16 + half * 8];
    acc[0][0] = __builtin_amdgcn_mfma_f32_32x32x16_bf16(a0, b0, acc[0][0], 0, 0, 0);
    acc[0][1] = __builtin_amdgcn_mfma_f32_32x32x16_bf16(a0, b1, acc[0][1], 0, 0, 0);
    acc[1][0] = __builtin_amdgcn_mfma_f32_32x32x16_bf16(a1, b0, acc[1][0], 0, 0, 0);
    acc[1][1] = __builtin_amdgcn_mfma_f32_32x32x16_bf16(a1, b1, acc[1][1], 0, 0, 0);
  }
  asm volatile("s_waitcnt vmcnt(0)" ::: "memory");  // drain tail DMA before slot reuse

  // ---- write per-wave partial into padded LDS region [64][68] f32 ----
  float* red = (float*)slot;
#pragma unroll
  for (int ti = 0; ti < 2; ++ti)
#pragma unroll
    for (int tj = 0; tj < 2; ++tj)
#pragma unroll
      for (int r = 0; r < 16; ++r) {
        int row = ti * 32 + (r & 3) + 8 * (r >> 2) + 4 * half;
        red[row * 68 + tj * 32 + l32] = acc[ti][tj][r];
      }
  __syncthreads();

  // ---- 4-way reduce + fused epilogue ----
  const int row = t >> 2, cs = (t & 3) * 16;
  const size_t orow = (size_t)(bm + row) * Nc + bn + cs;
#pragma unroll
  for (int u = 0; u < 4; ++u) {
    float4 s0 = *(const float4*)((const float*)(smem + 0 * 17408) + row * 68 + cs + u * 4);
    float4 s1 = *(const float4*)((const float*)(smem + 1 * 17408) + row * 68 + cs + u * 4);
    float4 s2 = *(const float4*)((const float*)(smem + 2 * 17408) + row * 68 + cs + u * 4);
    float4 s3 = *(const float4*)((const float*)(smem + 3 * 17408) + row * 68 + cs + u * 4);
    float o0 = s0.x + s1.x + s2.x + s3.x;
    float o1 = s0.y + s1.y + s2.y + s3.y;
    float o2 = s0.z + s1.z + s2.z + s3.z;
    float o3 = s0.w + s1.w + s2.w + s3.w;
    const int col = bn + cs + u * 4;
    if (mode == 0) {
      short4 w = {f2bf(o0), f2bf(o1), f2bf(o2), f2bf(o3)};
      *(short4*)&Cb[orow + u * 4] = w;
    } else if (mode == 1) {
      float4 bv = *(const float4*)&bvec[col];
      float4 rv = *(const float4*)&Cf[orow + u * 4];
      float4 w = {o0 + bv.x + rv.x, o1 + bv.y + rv.y, o2 + bv.z + rv.z, o3 + bv.w + rv.w};
      *(float4*)&Cf[orow + u * 4] = w;
    } else {
      float4 bv = *(const float4*)&bvec[col];
      short4 w = {f2bf(gelu_f(o0 + bv.x)), f2bf(gelu_f(o1 + bv.y)),
                  f2bf(gelu_f(o2 + bv.z)), f2bf(gelu_f(o3 + bv.w))};
      *(short4*)&Cb[orow + u * 4] = w;
    }
  }
}

// ---------------- MFMA flash attention: S^T orientation, 1 barrier/ktile, bf16 bias ----------------
__global__ __launch_bounds__(256) void attn_mfma_kernel(
    const short* __restrict__ qkv, const short* __restrict__ bias,
    short* __restrict__ o)
{
  constexpr int LDR = 72;
  __shared__ __align__(16) short Qs[64 * LDR];
  __shared__ __align__(16) short Ks[2][64 * LDR];
  __shared__ __align__(16) short Vt[2][64 * LDR];
  __shared__ __align__(16) short Ps[4 * 16 * LDR];

  const int q0 = blockIdx.x * 64;
  const int hh = blockIdx.y;
  const int b  = blockIdx.z;
  const int t  = threadIdx.x;
  const int wave = t >> 6;
  const int lane = t & 63;
  const int quad = lane >> 4;
  const int ln16 = lane & 15;
  const int srow = t >> 2, sseg = t & 3;

  {
    const short* qb = qkv + (size_t)(b * N + q0 + srow) * QKVS + hh * 64 + sseg * 16;
    *(bf16x8*)&Qs[srow * LDR + sseg * 16] = *(const bf16x8*)qb;
    *(bf16x8*)&Qs[srow * LDR + sseg * 16 + 8] = *(const bf16x8*)(qb + 8);
  }
  __syncthreads();

  const int qrow = wave * 16 + ln16;
  const bf16x8 qf0 = *(const bf16x8*)&Qs[qrow * LDR + quad * 8];
  const bf16x8 qf1 = *(const bf16x8*)&Qs[qrow * LDR + 32 + quad * 8];

  float m_run = -1e30f, l_run = 0.f;
  f32x4 Oacc[4];
#pragma unroll
  for (int dt = 0; dt < 4; ++dt) Oacc[dt] = (f32x4){0.f, 0.f, 0.f, 0.f};

  short* Psw = Ps + wave * 16 * LDR;
  const short* brow = bias + (size_t)(b * N + q0 + wave * 16 + ln16) * N;
  const short* kb0 = qkv + (size_t)b * N * QKVS + 512 + hh * 64 + sseg * 16;
  const short* vb0 = qkv + (size_t)b * N * QKVS + 1024 + hh * 64 + sseg * 16;

  auto ldb4 = [&](int off) -> float4 {
    short4 s4 = *(const short4*)&brow[off];
    float4 f;
    f.x = bf2f(s4.x); f.y = bf2f(s4.y); f.z = bf2f(s4.z); f.w = bf2f(s4.w);
    return f;
  };

  bf16x8 k0r = *(const bf16x8*)(kb0 + (size_t)srow * QKVS);
  bf16x8 k1r = *(const bf16x8*)(kb0 + (size_t)srow * QKVS + 8);
  bf16x8 v0r = *(const bf16x8*)(vb0 + (size_t)srow * QKVS);
  bf16x8 v1r = *(const bf16x8*)(vb0 + (size_t)srow * QKVS + 8);
  float4 b4[4];
#pragma unroll
  for (int ks = 0; ks < 4; ++ks)
    b4[ks] = ldb4(ks * 16 + quad * 4);

  for (int kt = 0; kt < 16; ++kt) {
    const int p = kt & 1;
    *(bf16x8*)&Ks[p][srow * LDR + sseg * 16] = k0r;
    *(bf16x8*)&Ks[p][srow * LDR + sseg * 16 + 8] = k1r;
#pragma unroll
    for (int e = 0; e < 8; ++e) {
      Vt[p][(sseg * 16 + e) * LDR + srow] = v0r[e];
      Vt[p][(sseg * 16 + 8 + e) * LDR + srow] = v1r[e];
    }
    const int k0n = (kt + 1 < 16) ? (kt + 1) * 64 : 0;
    bf16x8 nk0 = *(const bf16x8*)(kb0 + (size_t)(k0n + srow) * QKVS);
    bf16x8 nk1 = *(const bf16x8*)(kb0 + (size_t)(k0n + srow) * QKVS + 8);
    bf16x8 nv0 = *(const bf16x8*)(vb0 + (size_t)(k0n + srow) * QKVS);
    bf16x8 nv1 = *(const bf16x8*)(vb0 + (size_t)(k0n + srow) * QKVS + 8);
    float4 bcur[4] = {b4[0], b4[1], b4[2], b4[3]};
#pragma unroll
    for (int ks = 0; ks < 4; ++ks)
      b4[ks] = ldb4(k0n + ks * 16 + quad * 4);
    asm volatile("s_waitcnt lgkmcnt(0)\n\ts_barrier" ::: "memory");

    float sv[4][4];
#pragma unroll
    for (int ks = 0; ks < 4; ++ks) {
      bf16x8 a0 = *(const bf16x8*)&Ks[p][(ks * 16 + ln16) * LDR + quad * 8];
      bf16x8 a1 = *(const bf16x8*)&Ks[p][(ks * 16 + ln16) * LDR + 32 + quad * 8];
      f32x4 z = (f32x4){0.f, 0.f, 0.f, 0.f};
      z = __builtin_amdgcn_mfma_f32_16x16x32_bf16(a0, qf0, z, 0, 0, 0);
      z = __builtin_amdgcn_mfma_f32_16x16x32_bf16(a1, qf1, z, 0, 0, 0);
#pragma unroll
      for (int r = 0; r < 4; ++r)
        sv[ks][r] = z[r] * 0.125f + (&bcur[ks].x)[r];
    }

    float mt = sv[0][0];
#pragma unroll
    for (int ks = 0; ks < 4; ++ks)
#pragma unroll
      for (int r = 0; r < 4; ++r) mt = fmaxf(mt, sv[ks][r]);
    mt = fmaxf(mt, __shfl_xor(mt, 16));
    mt = fmaxf(mt, __shfl_xor(mt, 32));
    const float m_new = fmaxf(m_run, mt);
    const float alpha = __expf(m_run - m_new);
    m_run = m_new;
    float rs = 0.f;
    float pv[4][4];
#pragma unroll
    for (int ks = 0; ks < 4; ++ks)
#pragma unroll
      for (int r = 0; r < 4; ++r) {
        float e = __expf(sv[ks][r] - m_new);
        pv[ks][r] = e;
        rs += e;
      }
    rs += __shfl_xor(rs, 16);
    rs += __shfl_xor(rs, 32);
    l_run = l_run * alpha + rs;
    float af[4];
#pragma unroll
    for (int r = 0; r < 4; ++r) af[r] = __shfl(alpha, quad * 4 + r);
#pragma unroll
    for (int dt = 0; dt < 4; ++dt)
#pragma unroll
      for (int r = 0; r < 4; ++r) Oacc[dt][r] *= af[r];

#pragma unroll
    for (int ks = 0; ks < 4; ++ks) {
      short4 pk = {f2bf(pv[ks][0]), f2bf(pv[ks][1]), f2bf(pv[ks][2]), f2bf(pv[ks][3])};
      *(short4*)&Psw[ln16 * LDR + ks * 16 + quad * 4] = pk;
    }

    bf16x8 ap0 = *(const bf16x8*)&Psw[ln16 * LDR + quad * 8];
    bf16x8 ap1 = *(const bf16x8*)&Psw[ln16 * LDR + 32 + quad * 8];
#pragma unroll
    for (int dt = 0; dt < 4; ++dt) {
      bf16x8 bv0 = *(const bf16x8*)&Vt[p][(dt * 16 + ln16) * LDR + quad * 8];
      bf16x8 bv1 = *(const bf16x8*)&Vt[p][(dt * 16 + ln16) * LDR + 32 + quad * 8];
      Oacc[dt] = __builtin_amdgcn_mfma_f32_16x16x32_bf16(ap0, bv0, Oacc[dt], 0, 0, 0);
      Oacc[dt] = __builtin_amdgcn_mfma_f32_16x16x32_bf16(ap1, bv1, Oacc[dt], 0, 0, 0);
    }

    k0r = nk0; k1r = nk1; v0r = nv0; v1r = nv1;
  }

  const float linv = 1.0f / l_run;
  float iv[4];
#pragma unroll
  for (int r = 0; r < 4; ++r) iv[r] = __shfl(linv, quad * 4 + r);
#pragma unroll
  for (int dt = 0; dt < 4; ++dt) {
#pragma unroll
    for (int r = 0; r < 4; ++r) {
      int row = q0 + wave * 16 + quad * 4 + r;
      o[(size_t)(b * N + row) * D + hh * 64 + dt * 16 + ln16] =
          f2bf(Oacc[dt][r] * iv[r]);
    }
  }
}

}  // namespace

extern "C" void kernel_launch(void* const* d_in, const int* in_sizes, int n_in,
                              void* d_out, int out_size, void* d_ws, size_t ws_size,
                              hipStream_t stream)
{
  const float* tokens  = (const float*)d_in[0];
  const float* xy      = (const float*)d_in[1];
  const float* Wq      = (const float*)d_in[2];
  const float* Wk      = (const float*)d_in[3];
  const float* Wv      = (const float*)d_in[4];
  const float* Wo      = (const float*)d_in[5];
  const float* bo      = (const float*)d_in[6];
  const float* W1      = (const float*)d_in[7];
  const float* b1      = (const float*)d_in[8];
  const float* W2      = (const float*)d_in[9];
  const float* b2      = (const float*)d_in[10];
  const float* g1      = (const float*)d_in[11];
  const float* be1     = (const float*)d_in[12];
  const float* g2      = (const float*)d_in[13];
  const float* be2     = (const float*)d_in[14];
  const float* gf      = (const float*)d_in[15];
  const float* bf      = (const float*)d_in[16];
  const int*   alive   = (const int*)d_in[17];
  const int*   species = (const int*)d_in[18];

  char* p = (char*)d_ws;
  short* biasb = (short*)p; p += (size_t)B * N * N * 2;      // 8.39 MB (bf16)
  float* x    = (float*)p; p += (size_t)M * D * 4;           // 8.39 MB
  short* h    = (short*)p; p += (size_t)M * D * 2;           // 4.19 MB
  short* qkv  = (short*)p; p += (size_t)M * DFFd * 2;        // 16.78 MB (ff aliases qkv)
  short* ff   = qkv;
  short* Wqkvt = (short*)p; p += (size_t)L * QKVS * D * 2;   // 9.44 MB
  short* Wot   = (short*)p; p += (size_t)L * D * D * 2;      // 3.15 MB
  short* W1t   = (short*)p; p += (size_t)L * DFFd * D * 2;   // 12.58 MB
  short* W2t   = (short*)p; p += (size_t)L * D * DFFd * 2;   // 12.58 MB

  hipMemcpyAsync(x, tokens, sizeof(float) * (size_t)M * D,
                 hipMemcpyDeviceToDevice, stream);
  bias_kernel<<<dim3(N / 256, N, B), 256, 0, stream>>>(xy, alive, species, biasb);

  wprep_kernel<<<dim3(16, 16, L), 256, 0, stream>>>(
      Wq, Wqkvt + (size_t)0 * D * D, D, D, (size_t)D * D, (size_t)QKVS * D);
  wprep_kernel<<<dim3(16, 16, L), 256, 0, stream>>>(
      Wk, Wqkvt + (size_t)1 * D * D, D, D, (size_t)D * D, (size_t)QKVS * D);
  wprep_kernel<<<dim3(16, 16, L), 256, 0, stream>>>(
      Wv, Wqkvt + (size_t)2 * D * D, D, D, (size_t)D * D, (size_t)QKVS * D);
  wprep_kernel<<<dim3(16, 16, L), 256, 0, stream>>>(
      Wo, Wot, D, D, (size_t)D * D, (size_t)D * D);
  wprep_kernel<<<dim3(16, 64, L), 256, 0, stream>>>(
      W1, W1t, D, DFFd, (size_t)D * DFFd, (size_t)DFFd * D);
  wprep_kernel<<<dim3(64, 16, L), 256, 0, stream>>>(
      W2, W2t, DFFd, D, (size_t)DFFd * D, (size_t)D * DFFd);

  for (int l = 0; l < L; ++l) {
    ln_kernel<<<M, 64, 0, stream>>>(x, g1 + l * D, be1 + l * D, nullptr, h);
    gemm_sk_kernel<<<dim3(QKVS / 64, M / 64), 256, 0, stream>>>(
        h, Wqkvt + (size_t)l * QKVS * D, nullptr, nullptr, qkv, D, QKVS, 0);
    attn_mfma_kernel<<<dim3(N / 64, H, B), 256, 0, stream>>>(qkv, biasb, h);
    gemm_sk_kernel<<<dim3(D / 64, M / 64), 256, 0, stream>>>(
        h, Wot + (size_t)l * D * D, bo + l * D, x, nullptr, D, D, 1);
    ln_kernel<<<M, 64, 0, stream>>>(x, g2 + l * D, be2 + l * D, nullptr, h);
    gemm_sk_kernel<<<dim3(DFFd / 64, M / 64), 256, 0, stream>>>(
        h, W1t + (size_t)l * DFFd * D, b1 + l * DFFd, nullptr, ff, D, DFFd, 2);
    gemm_sk_kernel<<<dim3(D / 64, M / 64), 256, 0, stream>>>(
        ff, W2t + (size_t)l * D * DFFd, b2 + l * D, x, nullptr, DFFd, D, 1);
  }
  ln_kernel<<<M, 64, 0, stream>>>(x, gf, bf, (float*)d_out, nullptr);
}

// Round 8
// 1199.113 us; speedup vs baseline: 1.1304x; 1.1304x over previous
//
#include <hip/hip_runtime.h>
#include <math.h>

namespace {

constexpr int B = 4, N = 1024, D = 512, H = 8, DHd = 64, L = 6, DFFd = 2048;
constexpr int M = B * N;           // 4096
constexpr int QKVS = 3 * D;        // 1536, qkv row stride
constexpr float NEG = -1000000000.0f;
constexpr float R2c = 100.0f;

typedef __attribute__((ext_vector_type(8))) short bf16x8;
typedef __attribute__((ext_vector_type(4))) float f32x4;
typedef __attribute__((ext_vector_type(16))) float f32x16;

__device__ __forceinline__ short f2bf(float f) {
  union { float f; unsigned u; } c; c.f = f;
  unsigned r = (c.u + 0x7fffu + ((c.u >> 16) & 1u)) >> 16;
  return (short)r;
}

__device__ __forceinline__ float bf2f(short s) {
  union { unsigned u; float f; } c;
  c.u = ((unsigned)(unsigned short)s) << 16;
  return c.f;
}

__device__ __forceinline__ float gelu_f(float x) {
  return 0.5f * x * (1.0f + erff(x * 0.70710678118654752f));
}

// ---------------- bias: (B,N,N) additive mask, bf16 ----------------
__global__ __launch_bounds__(256) void bias_kernel(
    const float* __restrict__ xy, const int* __restrict__ alive,
    const int* __restrict__ species, short* __restrict__ bias)
{
  int j = blockIdx.x * 256 + threadIdx.x;
  int i = blockIdx.y;
  int b = blockIdx.z;
  float xi = xy[((size_t)b * N + i) * 2 + 0];
  float yi = xy[((size_t)b * N + i) * 2 + 1];
  float xj = xy[((size_t)b * N + j) * 2 + 0];
  float yj = xy[((size_t)b * N + j) * 2 + 1];
  float dx = xi - xj, dy = yi - yj;
  float d2 = dx * dx + dy * dy;
  float bv = 0.0f;
  if (alive[b * N + j] == 0) bv += NEG;
  if (d2 > R2c) bv += NEG;
  int si = species[b * N + i], sj = species[b * N + j];
  bool ia = si < 2, ip = si == 2, ja = sj < 2, jp = sj == 2;
  if ((ia && jp) || (ip && ja)) bv += NEG;
  bias[((size_t)b * N + i) * N + j] = f2bf(bv);
}

// ---------------- weight prep: fp32 (K x Nc) -> bf16 transposed (Nc x K) ----------------
__global__ __launch_bounds__(256) void wprep_kernel(
    const float* __restrict__ src, short* __restrict__ dst,
    int K, int Nc, size_t srcLS, size_t dstLS)
{
  __shared__ float t[32][33];
  int k0 = blockIdx.x * 32, n0 = blockIdx.y * 32;
  src += (size_t)blockIdx.z * srcLS;
  dst += (size_t)blockIdx.z * dstLS;
  int r = threadIdx.x >> 5, c = threadIdx.x & 31;  // r: 0..7
#pragma unroll
  for (int i = 0; i < 4; ++i)
    t[r + i * 8][c] = src[(size_t)(k0 + r + i * 8) * Nc + n0 + c];
  __syncthreads();
#pragma unroll
  for (int i = 0; i < 4; ++i)
    dst[(size_t)(n0 + r + i * 8) * K + k0 + c] = f2bf(t[c][r + i * 8]);
}

// ---------------- LayerNorm: one wave per row of 512; bf16 or fp32 out ----------------
__global__ __launch_bounds__(64) void ln_kernel(
    const float* __restrict__ x, const float* __restrict__ g,
    const float* __restrict__ be, float* __restrict__ outf,
    short* __restrict__ outb)
{
  int row = blockIdx.x;
  int tid = threadIdx.x;
  const float* xr = x + (size_t)row * D;
  float v[8];
  float sum = 0.f;
#pragma unroll
  for (int i = 0; i < 8; ++i) { v[i] = xr[tid + i * 64]; sum += v[i]; }
#pragma unroll
  for (int off = 32; off > 0; off >>= 1) sum += __shfl_down(sum, off);
  sum = __shfl(sum, 0);
  float mean = sum * (1.0f / D);
  float vs = 0.f;
#pragma unroll
  for (int i = 0; i < 8; ++i) { float d = v[i] - mean; vs += d * d; }
#pragma unroll
  for (int off = 32; off > 0; off >>= 1) vs += __shfl_down(vs, off);
  vs = __shfl(vs, 0);
  float rstd = rsqrtf(vs * (1.0f / D) + 1e-5f);
#pragma unroll
  for (int i = 0; i < 8; ++i) {
    int c = tid + i * 64;
    float o = (v[i] - mean) * rstd * g[c] + be[c];
    if (outb) outb[(size_t)row * D + c] = f2bf(o);
    else      outf[(size_t)row * D + c] = o;
  }
}

// ---------------- split-K bf16 MFMA GEMM: register-direct fragments ----------------
// Block = 64x64 C-tile, 4 waves; wave w accumulates K-slice [w*K/4,(w+1)*K/4)
// into a 64x64 partial (2x2 mfma_f32_32x32x16_bf16). MFMA A/B fragments are
// loaded DIRECTLY from global memory (row-major A, B^T): per-lane contiguous
// 16B = one global_load_dwordx4 per fragment. No LDS staging, no barriers, no
// manual waitcnt in the K-loop -- the compiler software-pipelines the loads.
// LDS used only for the final 4-way cross-wave reduction + fused epilogue.
// mode 0: Cb=bf16(acc); mode 1: Cf=acc+bvec+Cf (in-place); mode 2: Cb=bf16(gelu(acc+bvec)).
template <int K>
__global__ __launch_bounds__(256, 2) void gemm_rd_kernel(
    const short* __restrict__ A, const short* __restrict__ Bt,
    const float* __restrict__ bvec, float* __restrict__ Cf,
    short* __restrict__ Cb, int Nc, int mode)
{
  constexpr int NKS = K >> 6;          // ksteps of 16 per wave (8 or 32)
  __shared__ __align__(16) float red[4][64 * 68];  // 69632 B
  const int bm = blockIdx.y * 64, bn = blockIdx.x * 64;
  const int t = threadIdx.x, wave = t >> 6, lane = t & 63;
  const int half = lane >> 5;          // k-half for 32x32x16 frags
  const int l32 = lane & 31;           // m or n within tile
  const int kw0 = wave * (K >> 2);

  const short* a0p = A + (size_t)(bm + l32) * K + kw0 + half * 8;
  const short* a1p = a0p + (size_t)32 * K;
  const short* b0p = Bt + (size_t)(bn + l32) * K + kw0 + half * 8;
  const short* b1p = b0p + (size_t)32 * K;

  f32x16 acc[2][2];
#pragma unroll
  for (int i = 0; i < 2; ++i)
#pragma unroll
    for (int j = 0; j < 2; ++j)
#pragma unroll
      for (int r = 0; r < 16; ++r) acc[i][j][r] = 0.f;

#pragma unroll 8
  for (int ks = 0; ks < NKS; ++ks) {
    const int ko = ks * 16;
    bf16x8 a0 = *(const bf16x8*)(a0p + ko);
    bf16x8 a1 = *(const bf16x8*)(a1p + ko);
    bf16x8 b0 = *(const bf16x8*)(b0p + ko);
    bf16x8 b1 = *(const bf16x8*)(b1p + ko);
    acc[0][0] = __builtin_amdgcn_mfma_f32_32x32x16_bf16(a0, b0, acc[0][0], 0, 0, 0);
    acc[0][1] = __builtin_amdgcn_mfma_f32_32x32x16_bf16(a0, b1, acc[0][1], 0, 0, 0);
    acc[1][0] = __builtin_amdgcn_mfma_f32_32x32x16_bf16(a1, b0, acc[1][0], 0, 0, 0);
    acc[1][1] = __builtin_amdgcn_mfma_f32_32x32x16_bf16(a1, b1, acc[1][1], 0, 0, 0);
  }

  // ---- per-wave partial into padded LDS [64][68] f32 ----
#pragma unroll
  for (int ti = 0; ti < 2; ++ti)
#pragma unroll
    for (int tj = 0; tj < 2; ++tj)
#pragma unroll
      for (int r = 0; r < 16; ++r) {
        int row = ti * 32 + (r & 3) + 8 * (r >> 2) + 4 * half;
        red[wave][row * 68 + tj * 32 + l32] = acc[ti][tj][r];
      }
  __syncthreads();

  // ---- 4-way reduce + fused epilogue ----
  const int row = t >> 2, cs = (t & 3) * 16;
  const size_t orow = (size_t)(bm + row) * Nc + bn + cs;
#pragma unroll
  for (int u = 0; u < 4; ++u) {
    float4 s0 = *(const float4*)&red[0][row * 68 + cs + u * 4];
    float4 s1 = *(const float4*)&red[1][row * 68 + cs + u * 4];
    float4 s2 = *(const float4*)&red[2][row * 68 + cs + u * 4];
    float4 s3 = *(const float4*)&red[3][row * 68 + cs + u * 4];
    float o0 = s0.x + s1.x + s2.x + s3.x;
    float o1 = s0.y + s1.y + s2.y + s3.y;
    float o2 = s0.z + s1.z + s2.z + s3.z;
    float o3 = s0.w + s1.w + s2.w + s3.w;
    const int col = bn + cs + u * 4;
    if (mode == 0) {
      short4 w = {f2bf(o0), f2bf(o1), f2bf(o2), f2bf(o3)};
      *(short4*)&Cb[orow + u * 4] = w;
    } else if (mode == 1) {
      float4 bv = *(const float4*)&bvec[col];
      float4 rv = *(const float4*)&Cf[orow + u * 4];
      float4 w = {o0 + bv.x + rv.x, o1 + bv.y + rv.y, o2 + bv.z + rv.z, o3 + bv.w + rv.w};
      *(float4*)&Cf[orow + u * 4] = w;
    } else {
      float4 bv = *(const float4*)&bvec[col];
      short4 w = {f2bf(gelu_f(o0 + bv.x)), f2bf(gelu_f(o1 + bv.y)),
                  f2bf(gelu_f(o2 + bv.z)), f2bf(gelu_f(o3 + bv.w))};
      *(short4*)&Cb[orow + u * 4] = w;
    }
  }
}

// ---------------- MFMA flash attention: S^T orientation, 1 barrier/ktile, bf16 bias ----------------
__global__ __launch_bounds__(256) void attn_mfma_kernel(
    const short* __restrict__ qkv, const short* __restrict__ bias,
    short* __restrict__ o)
{
  constexpr int LDR = 72;
  __shared__ __align__(16) short Qs[64 * LDR];
  __shared__ __align__(16) short Ks[2][64 * LDR];
  __shared__ __align__(16) short Vt[2][64 * LDR];
  __shared__ __align__(16) short Ps[4 * 16 * LDR];

  const int q0 = blockIdx.x * 64;
  const int hh = blockIdx.y;
  const int b  = blockIdx.z;
  const int t  = threadIdx.x;
  const int wave = t >> 6;
  const int lane = t & 63;
  const int quad = lane >> 4;
  const int ln16 = lane & 15;
  const int srow = t >> 2, sseg = t & 3;

  {
    const short* qb = qkv + (size_t)(b * N + q0 + srow) * QKVS + hh * 64 + sseg * 16;
    *(bf16x8*)&Qs[srow * LDR + sseg * 16] = *(const bf16x8*)qb;
    *(bf16x8*)&Qs[srow * LDR + sseg * 16 + 8] = *(const bf16x8*)(qb + 8);
  }
  __syncthreads();

  const int qrow = wave * 16 + ln16;
  const bf16x8 qf0 = *(const bf16x8*)&Qs[qrow * LDR + quad * 8];
  const bf16x8 qf1 = *(const bf16x8*)&Qs[qrow * LDR + 32 + quad * 8];

  float m_run = -1e30f, l_run = 0.f;
  f32x4 Oacc[4];
#pragma unroll
  for (int dt = 0; dt < 4; ++dt) Oacc[dt] = (f32x4){0.f, 0.f, 0.f, 0.f};

  short* Psw = Ps + wave * 16 * LDR;
  const short* brow = bias + (size_t)(b * N + q0 + wave * 16 + ln16) * N;
  const short* kb0 = qkv + (size_t)b * N * QKVS + 512 + hh * 64 + sseg * 16;
  const short* vb0 = qkv + (size_t)b * N * QKVS + 1024 + hh * 64 + sseg * 16;

  auto ldb4 = [&](int off) -> float4 {
    short4 s4 = *(const short4*)&brow[off];
    float4 f;
    f.x = bf2f(s4.x); f.y = bf2f(s4.y); f.z = bf2f(s4.z); f.w = bf2f(s4.w);
    return f;
  };

  bf16x8 k0r = *(const bf16x8*)(kb0 + (size_t)srow * QKVS);
  bf16x8 k1r = *(const bf16x8*)(kb0 + (size_t)srow * QKVS + 8);
  bf16x8 v0r = *(const bf16x8*)(vb0 + (size_t)srow * QKVS);
  bf16x8 v1r = *(const bf16x8*)(vb0 + (size_t)srow * QKVS + 8);
  float4 b4[4];
#pragma unroll
  for (int ks = 0; ks < 4; ++ks)
    b4[ks] = ldb4(ks * 16 + quad * 4);

  for (int kt = 0; kt < 16; ++kt) {
    const int p = kt & 1;
    *(bf16x8*)&Ks[p][srow * LDR + sseg * 16] = k0r;
    *(bf16x8*)&Ks[p][srow * LDR + sseg * 16 + 8] = k1r;
#pragma unroll
    for (int e = 0; e < 8; ++e) {
      Vt[p][(sseg * 16 + e) * LDR + srow] = v0r[e];
      Vt[p][(sseg * 16 + 8 + e) * LDR + srow] = v1r[e];
    }
    const int k0n = (kt + 1 < 16) ? (kt + 1) * 64 : 0;
    bf16x8 nk0 = *(const bf16x8*)(kb0 + (size_t)(k0n + srow) * QKVS);
    bf16x8 nk1 = *(const bf16x8*)(kb0 + (size_t)(k0n + srow) * QKVS + 8);
    bf16x8 nv0 = *(const bf16x8*)(vb0 + (size_t)(k0n + srow) * QKVS);
    bf16x8 nv1 = *(const bf16x8*)(vb0 + (size_t)(k0n + srow) * QKVS + 8);
    float4 bcur[4] = {b4[0], b4[1], b4[2], b4[3]};
#pragma unroll
    for (int ks = 0; ks < 4; ++ks)
      b4[ks] = ldb4(k0n + ks * 16 + quad * 4);
    asm volatile("s_waitcnt lgkmcnt(0)\n\ts_barrier" ::: "memory");

    float sv[4][4];
#pragma unroll
    for (int ks = 0; ks < 4; ++ks) {
      bf16x8 a0 = *(const bf16x8*)&Ks[p][(ks * 16 + ln16) * LDR + quad * 8];
      bf16x8 a1 = *(const bf16x8*)&Ks[p][(ks * 16 + ln16) * LDR + 32 + quad * 8];
      f32x4 z = (f32x4){0.f, 0.f, 0.f, 0.f};
      z = __builtin_amdgcn_mfma_f32_16x16x32_bf16(a0, qf0, z, 0, 0, 0);
      z = __builtin_amdgcn_mfma_f32_16x16x32_bf16(a1, qf1, z, 0, 0, 0);
#pragma unroll
      for (int r = 0; r < 4; ++r)
        sv[ks][r] = z[r] * 0.125f + (&bcur[ks].x)[r];
    }

    float mt = sv[0][0];
#pragma unroll
    for (int ks = 0; ks < 4; ++ks)
#pragma unroll
      for (int r = 0; r < 4; ++r) mt = fmaxf(mt, sv[ks][r]);
    mt = fmaxf(mt, __shfl_xor(mt, 16));
    mt = fmaxf(mt, __shfl_xor(mt, 32));
    const float m_new = fmaxf(m_run, mt);
    const float alpha = __expf(m_run - m_new);
    m_run = m_new;
    float rs = 0.f;
    float pv[4][4];
#pragma unroll
    for (int ks = 0; ks < 4; ++ks)
#pragma unroll
      for (int r = 0; r < 4; ++r) {
        float e = __expf(sv[ks][r] - m_new);
        pv[ks][r] = e;
        rs += e;
      }
    rs += __shfl_xor(rs, 16);
    rs += __shfl_xor(rs, 32);
    l_run = l_run * alpha + rs;
    float af[4];
#pragma unroll
    for (int r = 0; r < 4; ++r) af[r] = __shfl(alpha, quad * 4 + r);
#pragma unroll
    for (int dt = 0; dt < 4; ++dt)
#pragma unroll
      for (int r = 0; r < 4; ++r) Oacc[dt][r] *= af[r];

#pragma unroll
    for (int ks = 0; ks < 4; ++ks) {
      short4 pk = {f2bf(pv[ks][0]), f2bf(pv[ks][1]), f2bf(pv[ks][2]), f2bf(pv[ks][3])};
      *(short4*)&Psw[ln16 * LDR + ks * 16 + quad * 4] = pk;
    }

    bf16x8 ap0 = *(const bf16x8*)&Psw[ln16 * LDR + quad * 8];
    bf16x8 ap1 = *(const bf16x8*)&Psw[ln16 * LDR + 32 + quad * 8];
#pragma unroll
    for (int dt = 0; dt < 4; ++dt) {
      bf16x8 bv0 = *(const bf16x8*)&Vt[p][(dt * 16 + ln16) * LDR + quad * 8];
      bf16x8 bv1 = *(const bf16x8*)&Vt[p][(dt * 16 + ln16) * LDR + 32 + quad * 8];
      Oacc[dt] = __builtin_amdgcn_mfma_f32_16x16x32_bf16(ap0, bv0, Oacc[dt], 0, 0, 0);
      Oacc[dt] = __builtin_amdgcn_mfma_f32_16x16x32_bf16(ap1, bv1, Oacc[dt], 0, 0, 0);
    }

    k0r = nk0; k1r = nk1; v0r = nv0; v1r = nv1;
  }

  const float linv = 1.0f / l_run;
  float iv[4];
#pragma unroll
  for (int r = 0; r < 4; ++r) iv[r] = __shfl(linv, quad * 4 + r);
#pragma unroll
  for (int dt = 0; dt < 4; ++dt) {
#pragma unroll
    for (int r = 0; r < 4; ++r) {
      int row = q0 + wave * 16 + quad * 4 + r;
      o[(size_t)(b * N + row) * D + hh * 64 + dt * 16 + ln16] =
          f2bf(Oacc[dt][r] * iv[r]);
    }
  }
}

}  // namespace

extern "C" void kernel_launch(void* const* d_in, const int* in_sizes, int n_in,
                              void* d_out, int out_size, void* d_ws, size_t ws_size,
                              hipStream_t stream)
{
  const float* tokens  = (const float*)d_in[0];
  const float* xy      = (const float*)d_in[1];
  const float* Wq      = (const float*)d_in[2];
  const float* Wk      = (const float*)d_in[3];
  const float* Wv      = (const float*)d_in[4];
  const float* Wo      = (const float*)d_in[5];
  const float* bo      = (const float*)d_in[6];
  const float* W1      = (const float*)d_in[7];
  const float* b1      = (const float*)d_in[8];
  const float* W2      = (const float*)d_in[9];
  const float* b2      = (const float*)d_in[10];
  const float* g1      = (const float*)d_in[11];
  const float* be1     = (const float*)d_in[12];
  const float* g2      = (const float*)d_in[13];
  const float* be2     = (const float*)d_in[14];
  const float* gf      = (const float*)d_in[15];
  const float* bf      = (const float*)d_in[16];
  const int*   alive   = (const int*)d_in[17];
  const int*   species = (const int*)d_in[18];

  char* p = (char*)d_ws;
  short* biasb = (short*)p; p += (size_t)B * N * N * 2;      // 8.39 MB (bf16)
  float* x    = (float*)p; p += (size_t)M * D * 4;           // 8.39 MB
  short* h    = (short*)p; p += (size_t)M * D * 2;           // 4.19 MB
  short* qkv  = (short*)p; p += (size_t)M * DFFd * 2;        // 16.78 MB (ff aliases qkv)
  short* ff   = qkv;
  short* Wqkvt = (short*)p; p += (size_t)L * QKVS * D * 2;   // 9.44 MB
  short* Wot   = (short*)p; p += (size_t)L * D * D * 2;      // 3.15 MB
  short* W1t   = (short*)p; p += (size_t)L * DFFd * D * 2;   // 12.58 MB
  short* W2t   = (short*)p; p += (size_t)L * D * DFFd * 2;   // 12.58 MB

  hipMemcpyAsync(x, tokens, sizeof(float) * (size_t)M * D,
                 hipMemcpyDeviceToDevice, stream);
  bias_kernel<<<dim3(N / 256, N, B), 256, 0, stream>>>(xy, alive, species, biasb);

  wprep_kernel<<<dim3(16, 16, L), 256, 0, stream>>>(
      Wq, Wqkvt + (size_t)0 * D * D, D, D, (size_t)D * D, (size_t)QKVS * D);
  wprep_kernel<<<dim3(16, 16, L), 256, 0, stream>>>(
      Wk, Wqkvt + (size_t)1 * D * D, D, D, (size_t)D * D, (size_t)QKVS * D);
  wprep_kernel<<<dim3(16, 16, L), 256, 0, stream>>>(
      Wv, Wqkvt + (size_t)2 * D * D, D, D, (size_t)D * D, (size_t)QKVS * D);
  wprep_kernel<<<dim3(16, 16, L), 256, 0, stream>>>(
      Wo, Wot, D, D, (size_t)D * D, (size_t)D * D);
  wprep_kernel<<<dim3(16, 64, L), 256, 0, stream>>>(
      W1, W1t, D, DFFd, (size_t)D * DFFd, (size_t)DFFd * D);
  wprep_kernel<<<dim3(64, 16, L), 256, 0, stream>>>(
      W2, W2t, DFFd, D, (size_t)DFFd * D, (size_t)D * DFFd);

  for (int l = 0; l < L; ++l) {
    ln_kernel<<<M, 64, 0, stream>>>(x, g1 + l * D, be1 + l * D, nullptr, h);
    gemm_rd_kernel<512><<<dim3(QKVS / 64, M / 64), 256, 0, stream>>>(
        h, Wqkvt + (size_t)l * QKVS * D, nullptr, nullptr, qkv, QKVS, 0);
    attn_mfma_kernel<<<dim3(N / 64, H, B), 256, 0, stream>>>(qkv, biasb, h);
    gemm_rd_kernel<512><<<dim3(D / 64, M / 64), 256, 0, stream>>>(
        h, Wot + (size_t)l * D * D, bo + l * D, x, nullptr, D, 1);
    ln_kernel<<<M, 64, 0, stream>>>(x, g2 + l * D, be2 + l * D, nullptr, h);
    gemm_rd_kernel<512><<<dim3(DFFd / 64, M / 64), 256, 0, stream>>>(
        h, W1t + (size_t)l * DFFd * D, b1 + l * DFFd, nullptr, ff, DFFd, 2);
    gemm_rd_kernel<2048><<<dim3(D / 64, M / 64), 256, 0, stream>>>(
        ff, W2t + (size_t)l * D * DFFd, b2 + l * D, x, nullptr, D, 1);
  }
  ln_kernel<<<M, 64, 0, stream>>>(x, gf, bf, (float*)d_out, nullptr);
}